// Round 3
// baseline (1214.329 us; speedup 1.0000x reference)
//
#include <hip/hip_runtime.h>
#include <hip/hip_cooperative_groups.h>

namespace cg = cooperative_groups;

#define NB 16
#define NN 300000
#define PRE 2000
#define POST 1000
#define GRID 768
#define BLK 256
#define BPI 48          // blocks per image for data-parallel phases (768/16)
#define CHR 48          // nms chunk rows

typedef unsigned long long ull;

// ---------- workspace layout (bytes) ----------
static constexpr size_t OFF_HIST1   = 0;                       // 16*1024*4 = 65536
static constexpr size_t OFF_HIST2   = 65536;                   // 16*2048*4 = 131072
static constexpr size_t OFF_HIST3   = 196608;                  // 131072
static constexpr size_t OFF_CANDCNT = 327680;                  // 64 (pad 256)
static constexpr size_t OFF_EQCNT   = 327936;                  // 64 (pad 256)
static constexpr size_t OFF_BITMAP  = 328192;                  // 16*32*8 = 4096
static constexpr size_t OFF_B1      = 332288;
static constexpr size_t OFF_NEED1   = 332544;
static constexpr size_t OFF_B2      = 332800;
static constexpr size_t OFF_NEED2   = 333056;
static constexpr size_t OFF_B3      = 333312;
static constexpr size_t OFF_NEED3   = 333568;
static constexpr size_t OFF_NVALID  = 333824;
static constexpr size_t ZERO_BYTES  = 334080;                  // zeroed in phase 0
static constexpr size_t OFF_CAND    = 334080;                  // 16*2048*4
static constexpr size_t OFF_EQBUF   = 465152;                  // 16*8192*4
static constexpr size_t OFF_KEYS    = 989440;                  // 16*2048*8
static constexpr size_t OFF_BOXTMP  = 1251584;                 // 16*2048*16
static constexpr size_t OFF_SORTED  = 1775872;                 // 16*2000*16
static constexpr size_t OFF_MASK    = 2287872;                 // 16*2000*32*8

__device__ __forceinline__ unsigned f2u(float f){
  unsigned b = __float_as_uint(f);
  return (b & 0x80000000u) ? ~b : (b | 0x80000000u);
}

// ---------- shared-memory phase views (union via one raw buffer) ----------
struct CompactS { unsigned lc[1024]; unsigned le[256]; unsigned lcn, len_, baseC, baseE; };
struct NmsS {
  unsigned rowsLds[2048];
  unsigned cntw[32];
  unsigned wbaseS[32];
  int mcountS, mpS;
  ull cacheD[2][CHR * 32];
  ull keepP[32];
  ull keepLin[32];
  unsigned cntArr[32], preArr[32];
};
static_assert(sizeof(CompactS) <= 40448, "compact lds");
static_assert(sizeof(NmsS)     <= 40448, "nms lds");
// hist1: 8*1025*4 = 32800; rank: 2048*8 = 16384; mask: 2000*16 + 2000*4 = 40000 — all <= 40448

// ---------- generic descending rank-select over a histogram (16 blocks) ----------
__device__ void dev_scan(const unsigned* __restrict__ hist, int bins,
                         const unsigned* __restrict__ tgt, unsigned K0,
                         unsigned* __restrict__ outBin, unsigned* __restrict__ outNeed,
                         char* sm, int img, int t){
  unsigned* arr = (unsigned*)sm;
  const unsigned* hh = hist + img * bins;
  unsigned K = tgt ? tgt[img] : K0;
  int per = bins >> 8;
  unsigned s = 0;
  for (int q = 0; q < per; q++) s += hh[bins - 1 - (t * per + q)];
  arr[t] = s;
  __syncthreads();
  for (int off = 1; off < 256; off <<= 1){
    unsigned v = (t >= off) ? arr[t - off] : 0u;
    __syncthreads();
    arr[t] += v;
    __syncthreads();
  }
  unsigned incl = arr[t], excl = incl - s;
  if (excl < K && K <= incl){
    unsigned c = excl;
    for (int q = 0; q < per; q++){
      int b = bins - 1 - (t * per + q);
      unsigned cnt = hh[b];
      if (c + cnt >= K){ outBin[img] = (unsigned)b; outNeed[img] = K - c; break; }
      c += cnt;
    }
  }
}

// ---------- the fused pipeline: one cooperative launch, 12 grid syncs ----------
__global__ __launch_bounds__(BLK, 3) void mega(const float* __restrict__ cls,
                                               const float* __restrict__ reg,
                                               const float* __restrict__ anch,
                                               float* __restrict__ out,
                                               char* __restrict__ ws,
                                               int outFloats){
  __shared__ __align__(16) char sm[40448];
  cg::grid_group gg = cg::this_grid();
  const int bid = blockIdx.x, tid = threadIdx.x;
  const int gtid = bid * BLK + tid;

  unsigned* hist1   = (unsigned*)(ws + OFF_HIST1);
  unsigned* hist2   = (unsigned*)(ws + OFF_HIST2);
  unsigned* hist3   = (unsigned*)(ws + OFF_HIST3);
  unsigned* candCnt = (unsigned*)(ws + OFF_CANDCNT);
  unsigned* eqCnt   = (unsigned*)(ws + OFF_EQCNT);
  ull*      bitmap  = (ull*)     (ws + OFF_BITMAP);
  unsigned* b1      = (unsigned*)(ws + OFF_B1);
  unsigned* need1   = (unsigned*)(ws + OFF_NEED1);
  unsigned* b2      = (unsigned*)(ws + OFF_B2);
  unsigned* need2   = (unsigned*)(ws + OFF_NEED2);
  unsigned* b3      = (unsigned*)(ws + OFF_B3);
  unsigned* need3   = (unsigned*)(ws + OFF_NEED3);
  unsigned* nvalid  = (unsigned*)(ws + OFF_NVALID);
  unsigned* cand    = (unsigned*)(ws + OFF_CAND);
  unsigned* eqbuf   = (unsigned*)(ws + OFF_EQBUF);
  ull*      keys    = (ull*)     (ws + OFF_KEYS);
  float*    boxTmp  = (float*)   (ws + OFF_BOXTMP);
  float*    sorted  = (float*)   (ws + OFF_SORTED);
  ull*      maskG   = (ull*)     (ws + OFF_MASK);

  // ---- phase 0: zero counters/hists/bitmap + output ----
  {
    unsigned* z = (unsigned*)ws;
    for (int i = gtid; i < (int)(ZERO_BYTES / 4); i += GRID * BLK) z[i] = 0u;
    for (int i = gtid; i < outFloats; i += GRID * BLK) out[i] = 0.f;
  }
  gg.sync();

  // ---- phase 1: hist1 (top 10 bits, 8 replicated LDS copies) ----
  {
    unsigned* h = (unsigned*)sm;
    int img = bid / BPI, sub = bid % BPI;
    for (int i = tid; i < 8 * 1025; i += BLK) h[i] = 0;
    __syncthreads();
    const float* p = cls + (size_t)img * NN;
    unsigned rep = (tid & 7) * 1025;
    for (int i = sub * BLK + tid; i < NN; i += BPI * BLK)
      atomicAdd(&h[rep + (f2u(p[i]) >> 22)], 1u);
    __syncthreads();
    unsigned* g = hist1 + img * 1024;
    for (int i = tid; i < 1024; i += BLK){
      unsigned v = 0;
      #pragma unroll
      for (int r = 0; r < 8; r++) v += h[r * 1025 + i];
      if (v) atomicAdd(&g[i], v);
    }
  }
  gg.sync();

  // ---- phase 2: scan1 ----
  if (bid < NB) dev_scan(hist1, 1024, (const unsigned*)nullptr, 2000u, b1, need1, sm, bid, tid);
  gg.sync();

  // ---- phase 3: hist2 (bits 21..11 within b1) ----
  {
    int img = bid / BPI, sub = bid % BPI;
    unsigned bb1 = b1[img];
    const float* p = cls + (size_t)img * NN;
    unsigned* g = hist2 + img * 2048;
    for (int i = sub * BLK + tid; i < NN; i += BPI * BLK){
      unsigned u = f2u(p[i]);
      if ((u >> 22) == bb1) atomicAdd(&g[(u >> 11) & 0x7FFu], 1u);
    }
  }
  gg.sync();

  // ---- phase 4: scan2 ----
  if (bid < NB) dev_scan(hist2, 2048, need1, 0u, b2, need2, sm, bid, tid);
  gg.sync();

  // ---- phase 5: hist3 (bits 10..0 within (b1,b2)) ----
  {
    int img = bid / BPI, sub = bid % BPI;
    unsigned pref = (b1[img] << 11) | b2[img];
    const float* p = cls + (size_t)img * NN;
    unsigned* g = hist3 + img * 2048;
    for (int i = sub * BLK + tid; i < NN; i += BPI * BLK){
      unsigned u = f2u(p[i]);
      if ((u >> 11) == pref) atomicAdd(&g[u & 0x7FFu], 1u);
    }
  }
  gg.sync();

  // ---- phase 6: scan3 ----
  if (bid < NB) dev_scan(hist3, 2048, need2, 0u, b3, need3, sm, bid, tid);
  gg.sync();

  // ---- phase 7: compact (u>T -> cand ; u==T -> eqbuf, LDS-aggregated) ----
  {
    CompactS* cs = (CompactS*)sm;
    int img = bid / BPI, sub = bid % BPI;
    if (tid == 0){ cs->lcn = 0; cs->len_ = 0; }
    __syncthreads();
    unsigned T = (b1[img] << 22) | (b2[img] << 11) | b3[img];
    const float* p = cls + (size_t)img * NN;
    for (int i = sub * BLK + tid; i < NN; i += BPI * BLK){
      unsigned u = f2u(p[i]);
      if (u > T){
        unsigned pos = atomicAdd(&cs->lcn, 1u);
        if (pos < 1024u) cs->lc[pos] = (unsigned)i;
        else { unsigned g2 = atomicAdd(&candCnt[img], 1u); if (g2 < 2048u) cand[img * 2048 + g2] = (unsigned)i; }
      } else if (u == T){
        unsigned pos = atomicAdd(&cs->len_, 1u);
        if (pos < 256u) cs->le[pos] = (unsigned)i;
        else { unsigned g2 = atomicAdd(&eqCnt[img], 1u); if (g2 < 8192u) eqbuf[img * 8192 + g2] = (unsigned)i; }
      }
    }
    __syncthreads();
    unsigned nc = cs->lcn < 1024u ? cs->lcn : 1024u;
    unsigned ne = cs->len_ < 256u ? cs->len_ : 256u;
    if (tid == 0){
      if (nc) cs->baseC = atomicAdd(&candCnt[img], nc);
      if (ne) cs->baseE = atomicAdd(&eqCnt[img], ne);
    }
    __syncthreads();
    for (unsigned t = tid; t < nc; t += BLK){
      unsigned g2 = cs->baseC + t;
      if (g2 < 2048u) cand[img * 2048 + g2] = cs->lc[t];
    }
    for (unsigned t = tid; t < ne; t += BLK){
      unsigned g2 = cs->baseE + t;
      if (g2 < 8192u) eqbuf[img * 8192 + g2] = cs->le[t];
    }
  }
  gg.sync();

  // ---- phase 8: finalize ties at threshold (rank by index among exact dups) ----
  if (bid < NB){
    int img = bid;
    unsigned need = need3[img];
    unsigned ec = eqCnt[img]; if (ec > 8192u) ec = 8192u;
    unsigned base = candCnt[img];
    const unsigned* eq = eqbuf + img * 8192;
    unsigned* c = cand + img * 2048;
    if (need >= ec){
      for (unsigned t = tid; t < ec; t += BLK) if (base + t < 2048u) c[base + t] = eq[t];
    } else {
      for (unsigned t = tid; t < ec; t += BLK){
        unsigned v = eq[t], r = 0;
        for (unsigned s2 = 0; s2 < ec; s2++) r += (eq[s2] < v) ? 1u : 0u;
        if (r < need && base + r < 2048u) c[base + r] = v;
      }
    }
  }
  gg.sync();

  // ---- phase 9: decode + clip + validity + key ----
  if (bid < 128){
    int s = bid * BLK + tid;
    int img = s >> 11, slot = s & 2047;
    ull key = 0ull;
    float4 box = make_float4(0.f, 0.f, 0.f, 0.f);
    bool counted = false;
    if (slot < PRE){
      unsigned i = cand[img * 2048 + slot];
      if (i < NN){
        size_t gi = (size_t)img * NN + i;
        float4 a = ((const float4*)anch)[gi];
        float4 r = ((const float4*)reg)[gi];
        float sc = cls[gi];
        float aw = a.z - a.x, ah = a.w - a.y;
        float acx = a.x + 0.5f * aw, acy = a.y + 0.5f * ah;
        float pcx = r.x * aw + acx, pcy = r.y * ah + acy;
        float pw = expf(r.z) * aw, ph = expf(r.w) * ah;
        float x1 = pcx - 0.5f * pw, y1 = pcy - 0.5f * ph;
        float x2 = pcx + 0.5f * pw, y2 = pcy + 0.5f * ph;
        x1 = fminf(fmaxf(x1, 0.f), 1333.f); x2 = fminf(fmaxf(x2, 0.f), 1333.f);
        y1 = fminf(fmaxf(y1, 0.f), 800.f);  y2 = fminf(fmaxf(y2, 0.f), 800.f);
        bool valid = ((x2 - x1) >= 0.001f) && ((y2 - y1) >= 0.001f);
        unsigned up = valid ? f2u(sc) : 0u;
        key = ((ull)up << 32) | (ull)(0xFFFFFFFFu - i);   // score desc, index asc
        box = make_float4(x1, y1, x2, y2);
        counted = valid;
      }
    }
    keys[img * 2048 + slot] = key;
    ((float4*)boxTmp)[img * 2048 + slot] = box;
    ull bal = __ballot(counted);
    if ((tid & 63) == 0 && bal)
      atomicAdd(&nvalid[img], (unsigned)__popcll(bal));
  }
  gg.sync();

  // ---- phase 10: rank-by-counting sort + scatter ----
  if (bid < 128){
    ull* lk = (ull*)sm;
    int img = bid >> 3;
    int e = (bid & 7) * 256 + tid;
    for (int t = tid; t < 2048; t += BLK) lk[t] = keys[img * 2048 + t];
    __syncthreads();
    ull me = lk[e];
    unsigned rank = 0;
    #pragma unroll 8
    for (int j = 0; j < 2048; j++) rank += (lk[j] > me) ? 1u : 0u;
    if (rank < PRE)
      ((float4*)sorted)[img * PRE + rank] = ((const float4*)boxTmp)[img * 2048 + e];
  }
  gg.sync();

  // ---- phase 11: suppression bitmask (permuted: word w bit q <-> j=32q+w) ----
  {
    float4* bx = (float4*)sm;
    float*  ar = (float*)(sm + PRE * sizeof(float4));
    int img = bid / BPI, sub = bid % BPI;
    for (int i = tid; i < PRE; i += BLK){
      float4 b = ((const float4*)sorted)[img * PRE + i];
      bx[i] = b;
      ar[i] = (b.z - b.x) * (b.w - b.y);
    }
    int nv = (int)nvalid[img];
    __syncthreads();
    int w = tid & 31;
    int rsub = tid >> 5;                         // 0..7 rows per unit
    int qhi = ((PRE - 1 - w) >> 5) + 1;
    for (int u = sub; u < PRE / 8; u += BPI){    // 250 units of 8 rows, strided
      int row = u * 8 + rsub;
      float4 bi = bx[row];
      float ai = ar[row];
      int qlo = (row >= w) ? (((row - w) >> 5) + 1) : 0;
      ull m = 0;
      for (int q = qlo; q < qhi; q++){
        int j = (q << 5) + w;
        float4 bj = bx[j];
        float xx1 = fmaxf(bi.x, bj.x), yy1 = fmaxf(bi.y, bj.y);
        float xx2 = fminf(bi.z, bj.z), yy2 = fminf(bi.w, bj.w);
        float ww = fmaxf(xx2 - xx1, 0.f), hh = fmaxf(yy2 - yy1, 0.f);
        float inter = ww * hh;
        float uni = ai + ar[j] - inter;
        if (inter / fmaxf(uni, 1e-8f) > 0.7f) m |= (1ull << q);   // exact div (bit-match)
      }
      maskG[((size_t)(img * PRE + row)) * 32 + w] = m;
      ull nz = __ballot(m != 0ull);              // wave = 2 rows (lanes 0..31 / 32..63)
      int lane = tid & 63;
      if (lane == 0 || lane == 32){
        ull half = (lane == 0) ? (nz & 0xFFFFFFFFull) : (nz >> 32);
        if (half && row < nv)
          atomicOr(&bitmap[img * 32 + (row >> 6)], 1ull << (row & 63));
      }
    }
  }
  gg.sync();

  // ---- phase 12: serial NMS scan (latency-optimized, verified round-2 body) ----
  if (bid < NB){
    NmsS* ns = (NmsS*)sm;
    int img = bid;
    int lane = tid & 63, wave = tid >> 6;

    if (tid < 32) ns->cntw[tid] = (unsigned)__popcll(bitmap[img * 32 + tid]);
    __syncthreads();
    if (tid == 0){
      unsigned s2 = 0;
      for (int w0 = 0; w0 < 32; w0++){ ns->wbaseS[w0] = s2; s2 += ns->cntw[w0]; }
      ns->mcountS = (int)s2;
      ns->mpS = ((int)s2 + CHR - 1) / CHR * CHR;
    }
    __syncthreads();
    int m = ns->mcountS, mp = ns->mpS;
    if (tid < 32){
      ull bits = bitmap[img * 32 + tid];
      unsigned pos = ns->wbaseS[tid];
      int base_i = tid * 64;
      while (bits){
        int b = __ffsll((long long)bits) - 1;
        ns->rowsLds[pos++] = (unsigned)(base_i + b);
        bits &= bits - 1;
      }
    }
    for (int t = m + tid; t < mp; t += BLK) ns->rowsLds[t] = PRE - 1;  // zero-mask pad row
    __syncthreads();

    int nch = mp / CHR;
    ull remv = 0;
    const ull* mg = maskG + (size_t)img * PRE * 32;

    if (nch > 0 && tid >= 64){
      int s2 = tid - 64;
      ull v[8];
      #pragma unroll
      for (int k = 0; k < 8; k++){
        int t = k * 192 + s2;
        unsigned rr = ns->rowsLds[t >> 5];
        v[k] = mg[(size_t)rr * 32 + (t & 31)];
      }
      #pragma unroll
      for (int k = 0; k < 8; k++) ns->cacheD[0][k * 192 + s2] = v[k];
    }
    __syncthreads();

    for (int c = 0; c < nch; c++){
      int cb = c & 1;
      if (tid >= 64){
        if (c + 1 < nch){
          int q0n = (c + 1) * CHR;
          int s2 = tid - 64;
          ull v[8];
          #pragma unroll
          for (int k = 0; k < 8; k++){
            int t = k * 192 + s2;
            unsigned rr = ns->rowsLds[q0n + (t >> 5)];
            v[k] = mg[(size_t)rr * 32 + (t & 31)];
          }
          #pragma unroll
          for (int k = 0; k < 8; k++) ns->cacheD[cb ^ 1][k * 192 + s2] = v[k];
        }
      } else {
        const ull* cbuf = ns->cacheD[cb];
        const int q0 = c * CHR;
        ull cur[8]; unsigned ci[8];
        #pragma unroll
        for (int k = 0; k < 8; k++){
          ci[k] = ns->rowsLds[q0 + k];
          cur[k] = cbuf[(k << 5) | (lane & 31)];
        }
        #pragma unroll
        for (int g2 = 0; g2 < 6; g2++){
          ull nxt[8]; unsigned ni[8];
          if (g2 < 5){
            #pragma unroll
            for (int k = 0; k < 8; k++){
              int lq = (g2 + 1) * 8 + k;
              ni[k] = ns->rowsLds[q0 + lq];
              nxt[k] = cbuf[(lq << 5) | (lane & 31)];
            }
          }
          #pragma unroll
          for (int k = 0; k < 8; k++){
            unsigned i = ci[k];
            unsigned bit = ((unsigned)(remv >> (i >> 5))) & 1u;
            int sup = (lane == (int)(i & 31)) && bit;
            if (!__any(sup)) remv |= cur[k];
          }
          if (g2 < 5){
            #pragma unroll
            for (int k = 0; k < 8; k++){ cur[k] = nxt[k]; ci[k] = ni[k]; }
          }
        }
      }
      __syncthreads();
    }

    int nv = (int)nvalid[img];
    if (wave == 0 && lane < 32){
      int cnt2 = (nv > lane) ? (((nv - 1 - lane) >> 5) + 1) : 0;
      ull vm = (cnt2 >= 64) ? ~0ull : ((1ull << cnt2) - 1ull);
      ns->keepP[lane] = (~remv) & vm;
    }
    __syncthreads();
    if (tid < 32){   // permuted -> linear
      ull lin = 0;
      for (int kk = 0; kk < 64; kk++)
        lin |= ((ns->keepP[kk & 31] >> (2 * tid + (kk >> 5))) & 1ull) << kk;
      ns->keepLin[tid] = lin;
      ns->cntArr[tid] = (unsigned)__popcll(lin);
    }
    __syncthreads();
    if (tid < 32){
      unsigned pre = 0;
      for (int w0 = 0; w0 < tid; w0++) pre += ns->cntArr[w0];
      ns->preArr[tid] = pre;
    }
    __syncthreads();
    for (int i = tid; i < PRE; i += BLK){
      int w0 = i >> 6, b = i & 63;
      ull kw = ns->keepLin[w0];
      if ((kw >> b) & 1ull){
        unsigned rank = ns->preArr[w0] + (unsigned)__popcll(kw & ((1ull << b) - 1ull));
        if (rank < POST)
          ((float4*)out)[img * POST + rank] = ((const float4*)sorted)[img * PRE + i];
      }
    }
  }
}

extern "C" void kernel_launch(void* const* d_in, const int* in_sizes, int n_in,
                              void* d_out, int out_size, void* d_ws, size_t ws_size,
                              hipStream_t stream){
  const float* cls  = (const float*)d_in[0];
  const float* reg  = (const float*)d_in[1];
  const float* anch = (const float*)d_in[2];
  float* out = (float*)d_out;
  char* ws = (char*)d_ws;
  int outFloats = out_size;

  void* args[] = { (void*)&cls, (void*)&reg, (void*)&anch, (void*)&out, (void*)&ws, (void*)&outFloats };
  hipLaunchCooperativeKernel((const void*)mega, dim3(GRID), dim3(BLK), args, 0, stream);
}

// Round 4
// 307.853 us; speedup vs baseline: 3.9445x; 3.9445x over previous
//
#include <hip/hip_runtime.h>

#define NB 16
#define NN 300000
#define PRE 2000
#define POST 1000

typedef unsigned long long ull;

// ---------- workspace layout (bytes) ----------
static const size_t OFF_HIST1   = 0;                       // 16*1024*4 = 65536
static const size_t OFF_CANDCNT = 65536;                   // 64 (pad 256)
static const size_t OFF_BINCNT  = 65792;                   // 64 (pad 256)
static const size_t OFF_B1      = 66048;
static const size_t OFF_NEED1   = 66304;
static const size_t OFF_NVALID  = 66560;
static const size_t OFF_BITMAP  = 66816;                   // 16*32*8 = 4096
static const size_t ZERO_BYTES  = 70912;                   // memset region
static const size_t OFF_CAND    = 70912;                   // 16*2048*4 = 131072
static const size_t OFF_KEYS    = 201984;                  // 16*2048*8 = 262144
static const size_t OFF_BOXTMP  = 464128;                  // 16*2048*16 = 524288
static const size_t OFF_SORTED  = 988416;                  // 16*2000*16 = 512000
static const size_t OFF_MASK    = 1500416;                 // 16*2000*32*8 = 8192000 (end 9692416)
static const size_t OFF_BINBUF  = OFF_MASK;                // ALIAS: 16*8192*8 = 1MB, consumed by k_select
                                                           // before k_mask writes masks (serial stream)

__device__ __forceinline__ unsigned f2u(float f){
  unsigned b = __float_as_uint(f);
  return (b & 0x80000000u) ? ~b : (b | 0x80000000u);
}

// ---------- pass 1 histogram: top 10 bits (8 replicated LDS copies) ----------
#define H1REP 8
#define H1STRIDE 1025
__global__ void k_hist1(const float* __restrict__ cls, unsigned* __restrict__ hist){
  __shared__ unsigned h[H1REP * H1STRIDE];
  int img = blockIdx.y;
  for (int i = threadIdx.x; i < H1REP * H1STRIDE; i += blockDim.x) h[i] = 0;
  __syncthreads();
  const float* p = cls + (size_t)img * NN;
  int stride = gridDim.x * blockDim.x;
  unsigned rep = (threadIdx.x & (H1REP - 1)) * H1STRIDE;
  for (int i = blockIdx.x * blockDim.x + threadIdx.x; i < NN; i += stride)
    atomicAdd(&h[rep + (f2u(p[i]) >> 22)], 1u);
  __syncthreads();
  unsigned* g = hist + img * 1024;
  for (int i = threadIdx.x; i < 1024; i += blockDim.x){
    unsigned v = 0;
    for (int r = 0; r < H1REP; r++) v += h[r * H1STRIDE + i];
    if (v) atomicAdd(&g[i], v);
  }
}

// ---------- descending rank-select over the 1024-bin histogram ----------
__global__ void k_scan(const unsigned* __restrict__ hist, int bins,
                       unsigned K0,
                       unsigned* __restrict__ outBin, unsigned* __restrict__ outNeed){
  int img = blockIdx.x;
  int t = threadIdx.x;
  const unsigned* hh = hist + img * bins;
  unsigned K = K0;
  int per = bins >> 8;
  unsigned s = 0;
  for (int q = 0; q < per; q++) s += hh[bins - 1 - (t * per + q)];
  __shared__ unsigned arr[256];
  arr[t] = s;
  __syncthreads();
  for (int off = 1; off < 256; off <<= 1){
    unsigned v = (t >= off) ? arr[t - off] : 0u;
    __syncthreads();
    arr[t] += v;
    __syncthreads();
  }
  unsigned incl = arr[t], excl = incl - s;
  if (excl < K && K <= incl){
    unsigned c = excl;
    for (int q = 0; q < per; q++){
      int b = bins - 1 - (t * per + q);
      unsigned cnt = hh[b];
      if (c + cnt >= K){ outBin[img] = (unsigned)b; outNeed[img] = K - c; break; }
      c += cnt;
    }
  }
}

// ---------- compaction: top10 > b1 -> cand ; top10 == b1 -> binbuf (LDS-aggregated) ----------
__global__ void k_compactA(const float* __restrict__ cls, const unsigned* __restrict__ b1,
                           unsigned* __restrict__ cand, unsigned* __restrict__ candCnt,
                           ull* __restrict__ binbuf, unsigned* __restrict__ binCnt){
  __shared__ unsigned lc[1024];
  __shared__ ull lb[512];
  __shared__ unsigned lcn, lbn, baseC, baseB;
  int img = blockIdx.y;
  if (threadIdx.x == 0){ lcn = 0; lbn = 0; }
  __syncthreads();
  unsigned bb1 = b1[img];
  const float* p = cls + (size_t)img * NN;
  int stride = gridDim.x * blockDim.x;
  for (int i = blockIdx.x * blockDim.x + threadIdx.x; i < NN; i += stride){
    unsigned u = f2u(p[i]);
    unsigned top = u >> 22;
    if (top > bb1){
      unsigned pos = atomicAdd(&lcn, 1u);
      if (pos < 1024u) lc[pos] = (unsigned)i;
      else { unsigned g = atomicAdd(&candCnt[img], 1u); if (g < 2048u) cand[img * 2048 + g] = (unsigned)i; }
    } else if (top == bb1){
      ull e = ((ull)u << 32) | (unsigned)i;
      unsigned pos = atomicAdd(&lbn, 1u);
      if (pos < 512u) lb[pos] = e;
      else { unsigned g = atomicAdd(&binCnt[img], 1u); if (g < 8192u) binbuf[img * 8192 + g] = e; }
    }
  }
  __syncthreads();
  unsigned nc = lcn < 1024u ? lcn : 1024u;
  unsigned nb = lbn < 512u ? lbn : 512u;
  if (threadIdx.x == 0){
    if (nc) baseC = atomicAdd(&candCnt[img], nc);
    if (nb) baseB = atomicAdd(&binCnt[img], nb);
  }
  __syncthreads();
  for (unsigned t = threadIdx.x; t < nc; t += blockDim.x){
    unsigned g = baseC + t;
    if (g < 2048u) cand[img * 2048 + g] = lc[t];
  }
  for (unsigned t = threadIdx.x; t < nb; t += blockDim.x){
    unsigned g = baseB + t;
    if (g < 8192u) binbuf[img * 8192 + g] = lb[t];
  }
}

// ---------- in-LDS 2-level refinement over bin b1 (~6400 entries) + tie-rank + fused decode ----------
__global__ __launch_bounds__(256) void k_select(const float* __restrict__ cls,
                                                const float* __restrict__ reg,
                                                const float* __restrict__ anch,
                                                unsigned* __restrict__ cand,
                                                const unsigned* __restrict__ candCnt,
                                                const ull* __restrict__ binbuf,
                                                const unsigned* __restrict__ binCnt,
                                                const unsigned* __restrict__ need1,
                                                float* __restrict__ boxTmp,
                                                ull* __restrict__ keys,
                                                unsigned* __restrict__ nvalid){
  __shared__ unsigned hist[2048];
  __shared__ unsigned arr[256];
  __shared__ unsigned b2s, need2s, b3s, need3s;
  __shared__ unsigned tiePos[1024];
  __shared__ unsigned wcnt, tieCnt;
  int img = blockIdx.x, tid = threadIdx.x;
  unsigned bc = binCnt[img]; if (bc > 8192u) bc = 8192u;
  unsigned base = candCnt[img];
  unsigned need = need1[img];
  const ull* bb = binbuf + img * 8192;

  if (tid == 0){ wcnt = 0; tieCnt = 0; b2s = 0; need2s = 0; b3s = 0; need3s = 0; }
  // ---- S1: hist of bits 21..11 ----
  for (int i = tid; i < 2048; i += 256) hist[i] = 0;
  __syncthreads();
  for (unsigned t = tid; t < bc; t += 256){
    unsigned u = (unsigned)(bb[t] >> 32);
    atomicAdd(&hist[(u >> 11) & 0x7FFu], 1u);
  }
  __syncthreads();
  {
    unsigned s = 0;
    for (int q = 0; q < 8; q++) s += hist[2047 - (tid * 8 + q)];
    arr[tid] = s; __syncthreads();
    for (int off = 1; off < 256; off <<= 1){
      unsigned v = (tid >= off) ? arr[tid - off] : 0u;
      __syncthreads(); arr[tid] += v; __syncthreads();
    }
    unsigned incl = arr[tid], excl = incl - s;
    if (excl < need && need <= incl){
      unsigned c = excl;
      for (int q = 0; q < 8; q++){
        int b = 2047 - (tid * 8 + q);
        unsigned cnt = hist[b];
        if (c + cnt >= need){ b2s = (unsigned)b; need2s = need - c; break; }
        c += cnt;
      }
    }
  }
  __syncthreads();
  unsigned b2 = b2s, need2 = need2s;
  // ---- S2: hist of bits 10..0 where mid == b2 ----
  for (int i = tid; i < 2048; i += 256) hist[i] = 0;
  __syncthreads();
  for (unsigned t = tid; t < bc; t += 256){
    unsigned u = (unsigned)(bb[t] >> 32);
    if (((u >> 11) & 0x7FFu) == b2) atomicAdd(&hist[u & 0x7FFu], 1u);
  }
  __syncthreads();
  {
    unsigned s = 0;
    for (int q = 0; q < 8; q++) s += hist[2047 - (tid * 8 + q)];
    arr[tid] = s; __syncthreads();
    for (int off = 1; off < 256; off <<= 1){
      unsigned v = (tid >= off) ? arr[tid - off] : 0u;
      __syncthreads(); arr[tid] += v; __syncthreads();
    }
    unsigned incl = arr[tid], excl = incl - s;
    if (excl < need2 && need2 <= incl){
      unsigned c = excl;
      for (int q = 0; q < 8; q++){
        int b = 2047 - (tid * 8 + q);
        unsigned cnt = hist[b];
        if (c + cnt >= need2){ b3s = (unsigned)b; need3s = need2 - c; break; }
        c += cnt;
      }
    }
  }
  __syncthreads();
  unsigned b3 = b3s, need3 = need3s;
  // ---- S3: write takes, collect ties ----
  for (unsigned t = tid; t < bc; t += 256){
    ull e = bb[t];
    unsigned u = (unsigned)(e >> 32);
    unsigned mid = (u >> 11) & 0x7FFu, low = u & 0x7FFu;
    bool take = (mid > b2) || (mid == b2 && low > b3);
    bool tie  = (mid == b2) && (low == b3);
    if (take){
      unsigned p = atomicAdd(&wcnt, 1u);
      unsigned g = base + p;
      if (g < 2048u) cand[img * 2048 + g] = (unsigned)(e & 0xFFFFFFFFull);
    } else if (tie){
      unsigned p = atomicAdd(&tieCnt, 1u);
      if (p < 1024u) tiePos[p] = t;
    }
  }
  __syncthreads();
  unsigned above = wcnt;                 // == need - need3
  unsigned ec = tieCnt; if (ec > 1024u) ec = 1024u;
  // rank ties by index asc, keep the need3 smallest (order within cand irrelevant: keys fix it)
  for (unsigned t = tid; t < ec; t += 256){
    unsigned idx = (unsigned)(bb[tiePos[t]] & 0xFFFFFFFFull);
    unsigned r = 0;
    for (unsigned s = 0; s < ec; s++){
      unsigned idx2 = (unsigned)(bb[tiePos[s]] & 0xFFFFFFFFull);
      r += (idx2 < idx) ? 1u : 0u;
    }
    if (r < need3){
      unsigned g = base + above + r;
      if (g < 2048u) cand[img * 2048 + g] = idx;
    }
  }
  __syncthreads();
  // ---- fused decode + clip + validity + key for all 2048 slots of this image ----
  for (int slot = tid; slot < 2048; slot += 256){
    ull key = 0ull;
    float4 box = make_float4(0.f, 0.f, 0.f, 0.f);
    bool counted = false;
    if (slot < PRE){
      unsigned i = cand[img * 2048 + slot];
      if (i < NN){
        size_t gi = (size_t)img * NN + i;
        float4 a = ((const float4*)anch)[gi];
        float4 r = ((const float4*)reg)[gi];
        float sc = cls[gi];
        float aw = a.z - a.x, ah = a.w - a.y;
        float acx = a.x + 0.5f * aw, acy = a.y + 0.5f * ah;
        float pcx = r.x * aw + acx, pcy = r.y * ah + acy;
        float pw = expf(r.z) * aw, ph = expf(r.w) * ah;
        float x1 = pcx - 0.5f * pw, y1 = pcy - 0.5f * ph;
        float x2 = pcx + 0.5f * pw, y2 = pcy + 0.5f * ph;
        x1 = fminf(fmaxf(x1, 0.f), 1333.f); x2 = fminf(fmaxf(x2, 0.f), 1333.f);
        y1 = fminf(fmaxf(y1, 0.f), 800.f);  y2 = fminf(fmaxf(y2, 0.f), 800.f);
        bool valid = ((x2 - x1) >= 0.001f) && ((y2 - y1) >= 0.001f);
        unsigned up = valid ? f2u(sc) : 0u;
        key = ((ull)up << 32) | (ull)(0xFFFFFFFFu - i);   // score desc, index asc
        box = make_float4(x1, y1, x2, y2);
        counted = valid;
      }
    }
    keys[img * 2048 + slot] = key;
    ((float4*)boxTmp)[img * 2048 + slot] = box;
    ull bal = __ballot(counted);
    if ((tid & 63) == 0 && bal)
      atomicAdd(&nvalid[img], (unsigned)__popcll(bal));
  }
}

// ---------- rank-by-counting sort: rank = #{j : key_j > key_e}; scatter ----------
__global__ __launch_bounds__(256) void k_rank(const ull* __restrict__ keys,
                                              const float* __restrict__ boxTmp,
                                              float* __restrict__ sorted){
  __shared__ ull lk[2048];
  int img = blockIdx.y;
  int e = blockIdx.x * 256 + threadIdx.x;
  for (int t = threadIdx.x; t < 2048; t += 256) lk[t] = keys[img * 2048 + t];
  __syncthreads();
  ull me = lk[e];
  unsigned rank = 0;
  #pragma unroll 8
  for (int j = 0; j < 2048; j++) rank += (lk[j] > me) ? 1u : 0u;
  if (rank < PRE)
    ((float4*)sorted)[img * PRE + rank] = ((const float4*)boxTmp)[img * 2048 + e];
}

// ---------- suppression bitmask, PERMUTED layout: word w bit q <-> j = 32q+w ----------
__global__ __launch_bounds__(512) void k_mask(const float* __restrict__ sorted,
                                              const unsigned* __restrict__ nvalid,
                                              ull* __restrict__ mask, ull* __restrict__ bitmap){
  __shared__ float4 bx[PRE];
  __shared__ float  ar[PRE];
  __shared__ unsigned rowflag[16];
  int img = blockIdx.y, tid = threadIdx.x;
  if (tid < 16) rowflag[tid] = 0;
  for (int i = tid; i < PRE; i += 512){
    float4 b = ((const float4*)sorted)[img * PRE + i];
    bx[i] = b;
    ar[i] = (b.z - b.x) * (b.w - b.y);
  }
  __syncthreads();
  int row = blockIdx.x * 16 + (tid >> 5);
  int w = tid & 31;
  float4 bi = bx[row];
  float ai = ar[row];
  int qlo = (row >= w) ? (((row - w) >> 5) + 1) : 0;
  int qhi = ((PRE - 1 - w) >> 5) + 1;
  ull m = 0;
  for (int q = qlo; q < qhi; q++){
    int j = (q << 5) + w;
    float4 bj = bx[j];
    float xx1 = fmaxf(bi.x, bj.x), yy1 = fmaxf(bi.y, bj.y);
    float xx2 = fminf(bi.z, bj.z), yy2 = fminf(bi.w, bj.w);
    float ww = fmaxf(xx2 - xx1, 0.f), hh = fmaxf(yy2 - yy1, 0.f);
    float inter = ww * hh;
    float uni = ai + ar[j] - inter;
    if (inter / fmaxf(uni, 1e-8f) > 0.7f) m |= (1ull << q);   // exact div (bit-match)
  }
  mask[((size_t)(img * PRE + row)) * 32 + w] = m;
  if (m) atomicOr(&rowflag[tid >> 5], 1u);
  __syncthreads();
  if (tid < 16){
    int r = blockIdx.x * 16 + tid;
    if (rowflag[tid] && r < (int)nvalid[img])
      atomicOr(&bitmap[img * 32 + (r >> 6)], 1ull << (r & 63));
  }
}

// ---------- serial NMS scan (latency-optimized) + rank/scatter + zero-fill tail ----------
#define CHR 48
__global__ __launch_bounds__(256) void k_nms(const ull* __restrict__ mask,
                                             const ull* __restrict__ bitmap,
                                             const unsigned* __restrict__ nvalid,
                                             const float* __restrict__ sorted,
                                             float* __restrict__ out){
  __shared__ unsigned rowsLds[2048];
  __shared__ unsigned cntw[32];
  __shared__ unsigned wbaseS[32];
  __shared__ int mcountS, mpS;
  __shared__ ull cacheD[2][CHR * 32];
  __shared__ ull keepP[32];     // permuted keep: word w bit q -> j = 32q+w
  __shared__ ull keepLin[32];   // linear keep:   word w bit b -> i = 64w+b
  __shared__ unsigned cntArr[32], preArr[32];
  int img = blockIdx.x, tid = threadIdx.x;
  int lane = tid & 63, wave = tid >> 6;

  // ---- phase A: parallel ordered row-list build ----
  if (tid < 32) cntw[tid] = (unsigned)__popcll(bitmap[img * 32 + tid]);
  __syncthreads();
  if (tid == 0){
    unsigned s = 0;
    for (int w0 = 0; w0 < 32; w0++){ wbaseS[w0] = s; s += cntw[w0]; }
    mcountS = (int)s;
    mpS = ((int)s + CHR - 1) / CHR * CHR;
  }
  __syncthreads();
  int m = mcountS, mp = mpS;
  if (tid < 32){
    ull bits = bitmap[img * 32 + tid];
    unsigned pos = wbaseS[tid];
    int base_i = tid * 64;
    while (bits){
      int b = __ffsll((long long)bits) - 1;
      rowsLds[pos++] = (unsigned)(base_i + b);
      bits &= bits - 1;
    }
  }
  for (int t = m + tid; t < mp; t += 256) rowsLds[t] = PRE - 1;  // zero-mask pad row
  __syncthreads();

  // ---- phase B: double-buffered staged serial scan ----
  int nch = mp / CHR;
  ull remv = 0;
  const ull* mg = mask + (size_t)img * PRE * 32;

  if (nch > 0 && tid >= 64){
    int s = tid - 64;
    ull v[8];
    #pragma unroll
    for (int k = 0; k < 8; k++){
      int t = k * 192 + s;                 // 0..1535 = 48 rows * 32 words
      unsigned rr = rowsLds[t >> 5];
      v[k] = mg[(size_t)rr * 32 + (t & 31)];
    }
    #pragma unroll
    for (int k = 0; k < 8; k++) cacheD[0][k * 192 + s] = v[k];
  }
  __syncthreads();

  for (int c = 0; c < nch; c++){
    int cb = c & 1;
    if (tid >= 64){
      if (c + 1 < nch){
        int q0n = (c + 1) * CHR;
        int s = tid - 64;
        ull v[8];
        #pragma unroll
        for (int k = 0; k < 8; k++){
          int t = k * 192 + s;
          unsigned rr = rowsLds[q0n + (t >> 5)];
          v[k] = mg[(size_t)rr * 32 + (t & 31)];
        }
        #pragma unroll
        for (int k = 0; k < 8; k++) cacheD[cb ^ 1][k * 192 + s] = v[k];
      }
    } else {
      // wave 0: serial scan of 48 rows, pipelined 8 ahead
      const ull* cbuf = cacheD[cb];
      const int q0 = c * CHR;
      ull cur[8]; unsigned ci[8];
      #pragma unroll
      for (int k = 0; k < 8; k++){
        ci[k] = rowsLds[q0 + k];
        cur[k] = cbuf[(k << 5) | (lane & 31)];
      }
      #pragma unroll
      for (int g = 0; g < 6; g++){
        ull nxt[8]; unsigned ni[8];
        if (g < 5){
          #pragma unroll
          for (int k = 0; k < 8; k++){
            int lq = (g + 1) * 8 + k;
            ni[k] = rowsLds[q0 + lq];
            nxt[k] = cbuf[(lq << 5) | (lane & 31)];
          }
        }
        #pragma unroll
        for (int k = 0; k < 8; k++){
          unsigned i = ci[k];
          unsigned bit = ((unsigned)(remv >> (i >> 5))) & 1u;
          int sup = (lane == (int)(i & 31)) && bit;
          if (!__any(sup)) remv |= cur[k];
        }
        if (g < 5){
          #pragma unroll
          for (int k = 0; k < 8; k++){ cur[k] = nxt[k]; ci[k] = ni[k]; }
        }
      }
    }
    __syncthreads();
  }

  // ---- epilogue: keep mask -> compaction + zero-fill tail ----
  int nv = (int)nvalid[img];
  if (wave == 0 && lane < 32){
    int cnt2 = (nv > lane) ? (((nv - 1 - lane) >> 5) + 1) : 0;   // #valid q for this word
    ull vm = (cnt2 >= 64) ? ~0ull : ((1ull << cnt2) - 1ull);
    keepP[lane] = (~remv) & vm;
  }
  __syncthreads();
  if (tid < 32){   // permuted -> linear
    ull lin = 0;
    for (int kk = 0; kk < 64; kk++)
      lin |= ((keepP[kk & 31] >> (2 * tid + (kk >> 5))) & 1ull) << kk;
    keepLin[tid] = lin;
    cntArr[tid] = (unsigned)__popcll(lin);
  }
  __syncthreads();
  if (tid < 32){
    unsigned pre = 0;
    for (int w0 = 0; w0 < tid; w0++) pre += cntArr[w0];
    preArr[tid] = pre;
  }
  __syncthreads();
  int totK = (int)(preArr[31] + cntArr[31]);   // total kept
  for (int i = tid; i < PRE; i += 256){
    int w0 = i >> 6, b = i & 63;
    ull kw = keepLin[w0];
    if ((kw >> b) & 1ull){
      unsigned rank = preArr[w0] + (unsigned)__popcll(kw & ((1ull << b) - 1ull));
      if (rank < POST)
        ((float4*)out)[img * POST + rank] = ((const float4*)sorted)[img * PRE + i];
    }
  }
  for (int r = totK + tid; r < POST; r += 256)
    ((float4*)out)[img * POST + r] = make_float4(0.f, 0.f, 0.f, 0.f);
}

extern "C" void kernel_launch(void* const* d_in, const int* in_sizes, int n_in,
                              void* d_out, int out_size, void* d_ws, size_t ws_size,
                              hipStream_t stream){
  const float* cls  = (const float*)d_in[0];
  const float* reg  = (const float*)d_in[1];
  const float* anch = (const float*)d_in[2];
  float* out = (float*)d_out;
  char* ws = (char*)d_ws;

  unsigned* hist1   = (unsigned*)(ws + OFF_HIST1);
  unsigned* candCnt = (unsigned*)(ws + OFF_CANDCNT);
  unsigned* binCnt  = (unsigned*)(ws + OFF_BINCNT);
  unsigned* b1      = (unsigned*)(ws + OFF_B1);
  unsigned* need1   = (unsigned*)(ws + OFF_NEED1);
  unsigned* nvalid  = (unsigned*)(ws + OFF_NVALID);
  ull*      bitmap  = (ull*)     (ws + OFF_BITMAP);
  unsigned* cand    = (unsigned*)(ws + OFF_CAND);
  ull*      keys    = (ull*)     (ws + OFF_KEYS);
  float*    boxTmp  = (float*)   (ws + OFF_BOXTMP);
  float*    sorted  = (float*)   (ws + OFF_SORTED);
  ull*      maskG   = (ull*)     (ws + OFF_MASK);
  ull*      binbuf  = (ull*)     (ws + OFF_BINBUF);

  hipMemsetAsync(ws, 0, ZERO_BYTES, stream);

  k_hist1   <<<dim3(64, NB), 256, 0, stream>>>(cls, hist1);
  k_scan    <<<NB, 256, 0, stream>>>(hist1, 1024, 2000u, b1, need1);
  k_compactA<<<dim3(64, NB), 256, 0, stream>>>(cls, b1, cand, candCnt, binbuf, binCnt);
  k_select  <<<NB, 256, 0, stream>>>(cls, reg, anch, cand, candCnt, binbuf, binCnt,
                                     need1, boxTmp, keys, nvalid);
  k_rank    <<<dim3(8, NB), 256, 0, stream>>>(keys, boxTmp, sorted);
  k_mask    <<<dim3(PRE / 16, NB), 512, 0, stream>>>(sorted, nvalid, maskG, bitmap);
  k_nms     <<<NB, 256, 0, stream>>>(maskG, bitmap, nvalid, sorted, out);
}